// Round 17
// baseline (105.182 us; speedup 1.0000x reference)
//
#include <hip/hip_runtime.h>
#include <hip/hip_bf16.h>

typedef __attribute__((ext_vector_type(16))) float f32x16;
typedef __attribute__((ext_vector_type(8))) short short8v;
typedef __attribute__((ext_vector_type(8))) unsigned short ushort8v;

#define T_ROWS 16384
#define H_DIM  4096
#define E_NUM  64
#define TOPK   8
#define MROWS  64               // rows per block (= rows per CU)
#define KC     64               // k-chunk (floats)
#define NCH    (H_DIM / KC)     // 64 chunks
#define WIMG   8192             // bytes per W chunk image (hi plane only)
#define MASK_OFF ((size_t)NCH * WIMG)

__device__ __forceinline__ unsigned short f2bf(float f) {
    unsigned int u = __float_as_uint(f);
    unsigned int r = (u + 0x7fffu + ((u >> 16) & 1u)) >> 16;  // RNE
    return (unsigned short)r;
}
__device__ __forceinline__ float bf2f(unsigned short h) {
    return __uint_as_float(((unsigned int)h) << 16);
}
__device__ __forceinline__ void gload_lds16(const void* g, void* l) {
    __builtin_amdgcn_global_load_lds(
        (const __attribute__((address_space(1))) unsigned int*)g,
        (__attribute__((address_space(3))) unsigned int*)l, 16, 0, 0);
}

// ---- prep: per-chunk swizzled LDS images of W (bf16 HI only) + mask ----
// for ch in [0,64): 8KB = [row 0..63][128B, byte sb holds W[row][ch*64 +
// (sb^((row&7)<<4))/2] hi]  -> linear gload_lds lands the swizzled tile.
__global__ __launch_bounds__(256) void prep_w(
    const float* __restrict__ W, unsigned short* __restrict__ WS,
    const int* __restrict__ ids, int nids)
{
    const int g     = blockIdx.x * 256 + threadIdx.x;   // 32768 16B-groups
    const int byteo = g * 16;
    const int ch    = byteo >> 13;
    const int rem   = byteo & 8191;
    const int row   = rem >> 7;
    const int sb    = rem & 127;
    const int bc    = sb ^ ((row & 7) << 4);
    const float* src = W + (size_t)row * H_DIM + ch * KC + (bc >> 1);
    ushort8v o;
#pragma unroll
    for (int t = 0; t < 8; ++t) o[t] = f2bf(src[t]);
    *(ushort8v*)((char*)WS + byteo) = o;

    if (blockIdx.x == 0 && threadIdx.x == 0) {
        unsigned long long mb = 0;
        for (int t = 0; t < nids; ++t) {
            const int e = ids[t];
            if (e >= 0 && e < E_NUM) mb |= (1ull << e);
        }
        *(unsigned long long*)((char*)WS + MASK_OFF) = mb;
    }
}

// ---- main: grid 256 (1 block/CU), 512 thr = 8 waves; wave w ->
// (rg=w>>2, cg=(w>>1)&1, kh=w&1): 32 rows x 32 experts over K-half kh of
// each 64k chunk, mfma_32x32x16, hi-only W; counted-vmcnt pipeline. ----
__global__ __launch_bounds__(512) void router_main(
    const float* __restrict__ X, const unsigned short* __restrict__ WS,
    float* __restrict__ out)
{
    const int tid  = threadIdx.x;
    const int lane = tid & 63;
    const int w    = tid >> 6;        // 0..7
    const int kh   = w & 1;           // K half of the chunk
    const int cg   = (w >> 1) & 1;    // experts half
    const int rg   = w >> 2;          // row half
    const int rb   = blockIdx.x * MROWS;
    const int fr32 = lane & 31;
    const int fo   = lane >> 5;

    __shared__ char LDSRAW[49152];
    char* XF0 = LDSRAW;               // 16 KB X f32 [64][256B src-xor16]
    char* XF1 = LDSRAW + 16384;       // 16 KB
    char* WF0 = LDSRAW + 32768;       // 8 KB  W-hi swizzled tile
    char* WF1 = LDSRAW + 40960;       // 8 KB

    // X DMA coords: 2 insts/thread; inst (w,i): base=(w*2+i)*1024
    const int xrow0 = w * 8 + (lane >> 4);          // i=0 rows
    const int xrow1 = xrow0 + 4;                    // i=1 rows
    const int xq    = lane & 15;
    const int xgc0  = xq ^ (xrow0 & 15);
    const int xgc1  = xq ^ (xrow1 & 15);
    const float* xs0 = X + (size_t)(rb + xrow0) * H_DIM + xgc0 * 4;
    const float* xs1 = X + (size_t)(rb + xrow1) * H_DIM + xgc1 * 4;
    const int xd0 = (w * 2 + 0) * 1024 + lane * 16;
    const int xd1 = (w * 2 + 1) * 1024 + lane * 16;

    // W DMA coords: 1 inst/thread, linear from pre-swizzled image
    const char* wimg = (const char*)WS;
    const int   woff = w * 1024 + lane * 16;

    // frag-read coords
    const int arow = rg * 32 + fr32;
    const int a16  = arow & 15;
    const int brow = cg * 32 + fr32;
    const int bsw  = (brow & 7) << 4;

    f32x16 acc;
#pragma unroll
    for (int r = 0; r < 16; ++r) acc[r] = 0.f;

    auto stage = [&](int ch, char* xf, char* wf) {
        gload_lds16(wimg + (size_t)ch * WIMG + woff, wf + woff);
        gload_lds16(xs0 + ch * KC, xf + xd0);
        gload_lds16(xs1 + ch * KC, xf + xd1);
    };

    // ---- prologue: 2 chunks in flight ----
    stage(0, XF0, WF0);
    stage(1, XF1, WF1);

    for (int ch = 0; ch < NCH; ++ch) {
        if (ch < NCH - 1) { asm volatile("s_waitcnt vmcnt(3)" ::: "memory"); }
        else              { asm volatile("s_waitcnt vmcnt(0)" ::: "memory"); }
        __builtin_amdgcn_sched_barrier(0);
        __builtin_amdgcn_s_barrier();          // buf[cur] ready for all waves
        __builtin_amdgcn_sched_barrier(0);

        const char* xf = (ch & 1) ? XF1 : XF0;
        const char* wf = (ch & 1) ? WF1 : WF0;
#pragma unroll
        for (int ks = 0; ks < 2; ++ks) {
            // A: 8 f32 of row arow, k = kh*32 + ks*16 + fo*8 (src quads q0,q0+1)
            const int q0 = kh * 8 + ks * 4 + fo * 2;
            const float4 a0 = *(const float4*)(xf + arow * 256 + ((q0 ^ a16) << 4));
            const float4 a1 = *(const float4*)(xf + arow * 256 + (((q0 + 1) ^ a16) << 4));
            float v[8] = {a0.x, a0.y, a0.z, a0.w, a1.x, a1.y, a1.z, a1.w};
            short8v ah, al;
#pragma unroll
            for (int t = 0; t < 8; ++t) {
                const unsigned short hb = f2bf(v[t]);
                ah[t] = (short)hb;
                al[t] = (short)f2bf(v[t] - bf2f(hb));
            }
            // B: row brow, same k, from swizzled W tile
            const int sb0 = kh * 64 + ks * 32 + fo * 16;
            short8v bh = *(const short8v*)(wf + brow * 128 + (sb0 ^ bsw));
            acc = __builtin_amdgcn_mfma_f32_32x32x16_bf16(ah, bh, acc, 0, 0, 0);
            acc = __builtin_amdgcn_mfma_f32_32x32x16_bf16(al, bh, acc, 0, 0, 0);
        }

        asm volatile("s_waitcnt lgkmcnt(0)" ::: "memory");
        __builtin_amdgcn_sched_barrier(0);
        __builtin_amdgcn_s_barrier();          // all waves done reading buf[cur]
        __builtin_amdgcn_sched_barrier(0);
        if (ch + 2 < NCH)
            stage(ch + 2, (ch & 1) ? XF1 : XF0, (ch & 1) ? WF1 : WF0);
    }

    // ---- scoreboard: 2 kh-planes [2][64][68] f32, deterministic reduce ----
    __syncthreads();                       // no VMEM outstanding
    float* sm = (float*)LDSRAW;            // 34816 B < 49152
    // C/D layout (m74/m101): col = lane&31, row = (r&3)+8*(r>>2)+4*(lane>>5)
#pragma unroll
    for (int r = 0; r < 16; ++r) {
        const int row = (r & 3) + 8 * (r >> 2) + 4 * fo;
        sm[(kh * 64 + rg * 32 + row) * 68 + cg * 32 + fr32] = acc[r];
    }
    __syncthreads();
    if (w >= 4) return;                    // no barriers after this point

    const unsigned long long mbits =
        *(const unsigned long long*)((const char*)WS + MASK_OFF);

    const int fr = lane & 15;
    const int fq = lane >> 4;
    float* o_log = out;
    float* o_rw  = out + (size_t)T_ROWS * E_NUM;
    float* o_se  = o_rw + (size_t)T_ROWS * TOPK;

    // wave w handles rows w*16 .. w*16+15 with the value-verified epilogue
#pragma unroll
    for (int j = 0; j < 4; ++j) {
        const int row_l = w * 16 + fq * 4 + j;
        const int grow  = rb + row_l;
        float a0 = 0.f, a1 = 0.f, a2 = 0.f, a3 = 0.f;
#pragma unroll
        for (int p = 0; p < 2; ++p) {      // fixed-order kh reduction
            a0 += sm[(p * 64 + row_l) * 68 +  0 + fr];
            a1 += sm[(p * 64 + row_l) * 68 + 16 + fr];
            a2 += sm[(p * 64 + row_l) * 68 + 32 + fr];
            a3 += sm[(p * 64 + row_l) * 68 + 48 + fr];
        }
        float mv0 = ((mbits >> ( 0 + fr)) & 1) ? a0 : -10000.0f;
        float mv1 = ((mbits >> (16 + fr)) & 1) ? a1 : -10000.0f;
        float mv2 = ((mbits >> (32 + fr)) & 1) ? a2 : -10000.0f;
        float mv3 = ((mbits >> (48 + fr)) & 1) ? a3 : -10000.0f;
        o_log[(size_t)grow * 64 +  0 + fr] = mv0;
        o_log[(size_t)grow * 64 + 16 + fr] = mv1;
        o_log[(size_t)grow * 64 + 32 + fr] = mv2;
        o_log[(size_t)grow * 64 + 48 + fr] = mv3;

        float m = fmaxf(fmaxf(mv0, mv1), fmaxf(mv2, mv3));
#pragma unroll
        for (int off = 1; off < 16; off <<= 1) m = fmaxf(m, __shfl_xor(m, off));

        float tsum = 0.f, myv = 0.f;
        int   mye  = 0;
#pragma unroll
        for (int t = 0; t < TOPK; ++t) {
            float bv = mv0; int be = fr;
            if (mv1 > bv) { bv = mv1; be = 16 + fr; }
            if (mv2 > bv) { bv = mv2; be = 32 + fr; }
            if (mv3 > bv) { bv = mv3; be = 48 + fr; }
#pragma unroll
            for (int off = 1; off < 16; off <<= 1) {
                float ov = __shfl_xor(bv, off);
                int   oe = __shfl_xor(be, off);
                if (ov > bv || (ov == bv && oe < be)) { bv = ov; be = oe; }
            }
            const float pv = expf(bv - m);
            tsum += pv;
            if (fr == t) { myv = pv; mye = be; }
            if ((be & 15) == fr) {       // owner lane excludes winner
                const int bn = be >> 4;
                if      (bn == 0) mv0 = -3.4e38f;
                else if (bn == 1) mv1 = -3.4e38f;
                else if (bn == 2) mv2 = -3.4e38f;
                else              mv3 = -3.4e38f;
            }
        }
        if (fr < TOPK) {
            o_rw[(size_t)grow * TOPK + fr] = myv / tsum;
            o_se[(size_t)grow * TOPK + fr] = (float)mye;
        }
    }
}

extern "C" void kernel_launch(void* const* d_in, const int* in_sizes, int n_in,
                              void* d_out, int out_size, void* d_ws, size_t ws_size,
                              hipStream_t stream) {
    const float* X   = (const float*)d_in[0];
    const float* W   = (const float*)d_in[1];
    const int*   ids = (const int*)d_in[2];
    const int    nids = in_sizes[2];
    float* out = (float*)d_out;

    unsigned short* WS = (unsigned short*)d_ws;   // 512 KB W image + 8 B mask

    hipLaunchKernelGGL(prep_w, dim3(128), dim3(256), 0, stream, W, WS, ids, nids);
    hipLaunchKernelGGL(router_main, dim3(T_ROWS / MROWS), dim3(512), 0, stream,
                       X, WS, out);
}

// Round 18
// 77.861 us; speedup vs baseline: 1.3509x; 1.3509x over previous
//
#include <hip/hip_runtime.h>
#include <hip/hip_bf16.h>

typedef __attribute__((ext_vector_type(16))) float f32x16;
typedef __attribute__((ext_vector_type(8))) short short8v;
typedef __attribute__((ext_vector_type(8))) unsigned short ushort8v;

#define T_ROWS 16384
#define H_DIM  4096
#define E_NUM  64
#define TOPK   8
#define MROWS  64               // rows per block (= rows per CU)
#define KC     128              // k-chunk
#define NCH    (H_DIM / KC)     // 32 chunks
#define WIMG   16384            // bytes per W chunk image (hi plane, swizzled)
#define MASK_OFF ((size_t)NCH * WIMG)

__device__ __forceinline__ unsigned short f2bf(float f) {
    unsigned int u = __float_as_uint(f);
    unsigned int r = (u + 0x7fffu + ((u >> 16) & 1u)) >> 16;  // RNE
    return (unsigned short)r;
}
__device__ __forceinline__ float bf2f(unsigned short h) {
    return __uint_as_float(((unsigned int)h) << 16);
}
__device__ __forceinline__ void gload_lds16(const void* g, void* l) {
    __builtin_amdgcn_global_load_lds(
        (const __attribute__((address_space(1))) unsigned int*)g,
        (__attribute__((address_space(3))) unsigned int*)l, 16, 0, 0);
}

// ---- prep: per-chunk pre-swizzled W-hi tile images + allowed-mask ----
// for ch in [0,32): 16KB = [row 0..63][256B]; byte sb of row holds
// W[row][ch*128 + (sb^((row&15)<<4))/2] as bf16-hi -> linear DMA lands
// the XOR-swizzled tile.
__global__ __launch_bounds__(256) void prep_w(
    const float* __restrict__ W, unsigned short* __restrict__ WS,
    const int* __restrict__ ids, int nids)
{
    const int g     = blockIdx.x * 256 + threadIdx.x;   // 32768 16B-groups
    const int byteo = g * 16;
    const int ch    = byteo >> 14;
    const int rem   = byteo & 16383;
    const int row   = rem >> 8;
    const int sb    = rem & 255;
    const int bc    = sb ^ ((row & 15) << 4);
    const float* src = W + (size_t)row * H_DIM + ch * KC + (bc >> 1);
    ushort8v o;
#pragma unroll
    for (int t = 0; t < 8; ++t) o[t] = f2bf(src[t]);
    *(ushort8v*)((char*)WS + byteo) = o;

    if (blockIdx.x == 0 && threadIdx.x == 0) {
        unsigned long long mb = 0;
        for (int t = 0; t < nids; ++t) {
            const int e = ids[t];
            if (e >= 0 && e < E_NUM) mb |= (1ull << e);
        }
        *(unsigned long long*)((char*)WS + MASK_OFF) = mb;
    }
}

// ---- main: grid 256 (1 block/CU), 1024 thr = 16 waves; wave w ->
// (kh=w&3, cg=(w>>2)&1, rg=w>>3): 32 rows x 32 experts over K-quarter kh
// of each 128k chunk; W-hi DMA'd ONCE per CU into dbuf LDS tiles. ----
__global__ __launch_bounds__(1024) void router_main(
    const float* __restrict__ X, const unsigned short* __restrict__ WS,
    float* __restrict__ out)
{
    const int tid  = threadIdx.x;
    const int lane = tid & 63;
    const int w    = tid >> 6;        // 0..15
    const int kh   = w & 3;           // K quarter of the chunk
    const int cg   = (w >> 2) & 1;    // experts half
    const int rg   = w >> 3;          // row half
    const int rb   = blockIdx.x * MROWS;
    const int fr32 = lane & 31;
    const int fo   = lane >> 5;

    __shared__ char LDSRAW[65536];
    char* XH  = LDSRAW;               // 16 KB [64][256B xor16] X bf16-hi
    char* XL  = LDSRAW + 16384;       // 16 KB bf16-lo
    char* WT0 = LDSRAW + 32768;       // 16 KB W-hi swizzled tile (dbuf)
    char* WT1 = LDSRAW + 49152;       // 16 KB

    // X staging: 8 f32/thread
    const int srow  = tid >> 4;               // 0..63
    const int sc8   = (tid & 15) * 8;         // f32 col base
    const float* xg = X + (size_t)(rb + srow) * H_DIM + sc8;
    const int xbyte = srow * 256 + ((sc8 * 2) ^ ((srow & 15) << 4));

    // W DMA: 16 B/thread/chunk, linear from pre-swizzled image
    const char* wimg = (const char*)WS;
    const int   woff = w * 1024 + lane * 16;

    // frag-read coords
    const int arow = rg * 32 + fr32;
    const int asw  = (arow & 15) << 4;
    const int brow = cg * 32 + fr32;
    const int bsw  = (brow & 15) << 4;

    f32x16 acc;
#pragma unroll
    for (int r = 0; r < 16; ++r) acc[r] = 0.f;

    // ---- prologue: chunk-0 X regs + W DMA ----
    float4 px0 = *(const float4*)(xg);
    float4 px1 = *(const float4*)(xg + 4);
    gload_lds16(wimg + woff, WT0 + woff);

    for (int ch = 0; ch < NCH; ++ch) {
        __syncthreads();   // [A] prev compute done; drains this chunk's W DMA
        {
            float v[8] = {px0.x, px0.y, px0.z, px0.w,
                          px1.x, px1.y, px1.z, px1.w};
            ushort8v hv, lv;
#pragma unroll
            for (int t = 0; t < 8; ++t) {
                const unsigned short hb = f2bf(v[t]);
                hv[t] = hb;
                lv[t] = f2bf(v[t] - bf2f(hb));
            }
            *(ushort8v*)(XH + xbyte) = hv;
            *(ushort8v*)(XL + xbyte) = lv;
        }
        __syncthreads();   // [B] X tile ready; W tile ready since [A]
        if (ch + 1 < NCH) {
            const float* xn = xg + (ch + 1) * KC;
            px0 = *(const float4*)(xn);
            px1 = *(const float4*)(xn + 4);
            gload_lds16(wimg + (size_t)(ch + 1) * WIMG + woff,
                        ((ch & 1) ? WT0 : WT1) + woff);
        }
        const char* wt = (ch & 1) ? WT1 : WT0;
#pragma unroll
        for (int ks = 0; ks < 2; ++ks) {
            const int kb = kh * 64 + ks * 32 + fo * 16;
            short8v ah = *(const short8v*)(XH + arow * 256 + (kb ^ asw));
            short8v al = *(const short8v*)(XL + arow * 256 + (kb ^ asw));
            short8v bh = *(const short8v*)(wt + brow * 256 + (kb ^ bsw));
            acc = __builtin_amdgcn_mfma_f32_32x32x16_bf16(ah, bh, acc, 0, 0, 0);
            acc = __builtin_amdgcn_mfma_f32_32x32x16_bf16(al, bh, acc, 0, 0, 0);
        }
    }

    // ---- scoreboard: 2-round deterministic merge into [2][64][68] f32 ----
    __syncthreads();                       // all compute done
    float* sm = (float*)LDSRAW;            // 34816 B <= 65536
    // C/D layout (m74/m101): col = lane&31, row = (r&3)+8*(r>>2)+4*(lane>>5)
    if (kh < 2) {
#pragma unroll
        for (int r = 0; r < 16; ++r) {
            const int row = (r & 3) + 8 * (r >> 2) + 4 * fo;
            sm[(kh * 64 + rg * 32 + row) * 68 + cg * 32 + fr32] = acc[r];
        }
    }
    __syncthreads();
    if (kh >= 2) {
#pragma unroll
        for (int r = 0; r < 16; ++r) {
            const int row = (r & 3) + 8 * (r >> 2) + 4 * fo;
            sm[((kh - 2) * 64 + rg * 32 + row) * 68 + cg * 32 + fr32] += acc[r];
        }
    }
    __syncthreads();
    if (w >= 4) return;                    // no barriers after this point

    const unsigned long long mbits =
        *(const unsigned long long*)((const char*)WS + MASK_OFF);

    const int fr = lane & 15;
    const int fq = lane >> 4;
    float* o_log = out;
    float* o_rw  = out + (size_t)T_ROWS * E_NUM;
    float* o_se  = o_rw + (size_t)T_ROWS * TOPK;

    // wave w handles rows w*16 .. w*16+15 with the value-verified epilogue
#pragma unroll
    for (int j = 0; j < 4; ++j) {
        const int row_l = w * 16 + fq * 4 + j;
        const int grow  = rb + row_l;
        float a0 = 0.f, a1 = 0.f, a2 = 0.f, a3 = 0.f;
#pragma unroll
        for (int p = 0; p < 2; ++p) {      // fixed-order plane reduction
            a0 += sm[(p * 64 + row_l) * 68 +  0 + fr];
            a1 += sm[(p * 64 + row_l) * 68 + 16 + fr];
            a2 += sm[(p * 64 + row_l) * 68 + 32 + fr];
            a3 += sm[(p * 64 + row_l) * 68 + 48 + fr];
        }
        float mv0 = ((mbits >> ( 0 + fr)) & 1) ? a0 : -10000.0f;
        float mv1 = ((mbits >> (16 + fr)) & 1) ? a1 : -10000.0f;
        float mv2 = ((mbits >> (32 + fr)) & 1) ? a2 : -10000.0f;
        float mv3 = ((mbits >> (48 + fr)) & 1) ? a3 : -10000.0f;
        o_log[(size_t)grow * 64 +  0 + fr] = mv0;
        o_log[(size_t)grow * 64 + 16 + fr] = mv1;
        o_log[(size_t)grow * 64 + 32 + fr] = mv2;
        o_log[(size_t)grow * 64 + 48 + fr] = mv3;

        float m = fmaxf(fmaxf(mv0, mv1), fmaxf(mv2, mv3));
#pragma unroll
        for (int off = 1; off < 16; off <<= 1) m = fmaxf(m, __shfl_xor(m, off));

        float tsum = 0.f, myv = 0.f;
        int   mye  = 0;
#pragma unroll
        for (int t = 0; t < TOPK; ++t) {
            float bv = mv0; int be = fr;
            if (mv1 > bv) { bv = mv1; be = 16 + fr; }
            if (mv2 > bv) { bv = mv2; be = 32 + fr; }
            if (mv3 > bv) { bv = mv3; be = 48 + fr; }
#pragma unroll
            for (int off = 1; off < 16; off <<= 1) {
                float ov = __shfl_xor(bv, off);
                int   oe = __shfl_xor(be, off);
                if (ov > bv || (ov == bv && oe < be)) { bv = ov; be = oe; }
            }
            const float pv = expf(bv - m);
            tsum += pv;
            if (fr == t) { myv = pv; mye = be; }
            if ((be & 15) == fr) {       // owner lane excludes winner
                const int bn = be >> 4;
                if      (bn == 0) mv0 = -3.4e38f;
                else if (bn == 1) mv1 = -3.4e38f;
                else if (bn == 2) mv2 = -3.4e38f;
                else              mv3 = -3.4e38f;
            }
        }
        if (fr < TOPK) {
            o_rw[(size_t)grow * TOPK + fr] = myv / tsum;
            o_se[(size_t)grow * TOPK + fr] = (float)mye;
        }
    }
}

extern "C" void kernel_launch(void* const* d_in, const int* in_sizes, int n_in,
                              void* d_out, int out_size, void* d_ws, size_t ws_size,
                              hipStream_t stream) {
    const float* X   = (const float*)d_in[0];
    const float* W   = (const float*)d_in[1];
    const int*   ids = (const int*)d_in[2];
    const int    nids = in_sizes[2];
    float* out = (float*)d_out;

    unsigned short* WS = (unsigned short*)d_ws;   // 512 KB W image + 8 B mask

    hipLaunchKernelGGL(prep_w, dim3(128), dim3(256), 0, stream, W, WS, ids, nids);
    hipLaunchKernelGGL(router_main, dim3(T_ROWS / MROWS), dim3(1024), 0, stream,
                       X, WS, out);
}

// Round 19
// 76.550 us; speedup vs baseline: 1.3740x; 1.0171x over previous
//
#include <hip/hip_runtime.h>
#include <hip/hip_bf16.h>

typedef __attribute__((ext_vector_type(16))) float f32x16;
typedef __attribute__((ext_vector_type(8))) short short8v;
typedef __attribute__((ext_vector_type(8))) unsigned short ushort8v;

#define T_ROWS 16384
#define H_DIM  4096
#define E_NUM  64
#define TOPK   8
#define MROWS  64               // rows per block (= rows per CU)
#define KC     128              // k-chunk
#define NCH    (H_DIM / KC)     // 32 chunks
#define WIMG   16384            // bytes per W chunk image (hi plane, swizzled)
#define MASK_OFF ((size_t)NCH * WIMG)

__device__ __forceinline__ unsigned short f2bf(float f) {
    unsigned int u = __float_as_uint(f);
    unsigned int r = (u + 0x7fffu + ((u >> 16) & 1u)) >> 16;  // RNE
    return (unsigned short)r;
}
__device__ __forceinline__ float bf2f(unsigned short h) {
    return __uint_as_float(((unsigned int)h) << 16);
}
__device__ __forceinline__ void gload_lds16(const void* g, void* l) {
    __builtin_amdgcn_global_load_lds(
        (const __attribute__((address_space(1))) unsigned int*)g,
        (__attribute__((address_space(3))) unsigned int*)l, 16, 0, 0);
}

// ---- prep: per-chunk pre-swizzled W-hi tile images + allowed-mask ----
// for ch in [0,32): 16KB = [row 0..63][256B]; byte sb of row holds
// W[row][ch*128 + (sb^((row&15)<<4))/2] as bf16-hi -> linear DMA lands
// the XOR-swizzled tile.
__global__ __launch_bounds__(256) void prep_w(
    const float* __restrict__ W, unsigned short* __restrict__ WS,
    const int* __restrict__ ids, int nids)
{
    const int g     = blockIdx.x * 256 + threadIdx.x;   // 32768 16B-groups
    const int byteo = g * 16;
    const int ch    = byteo >> 14;
    const int rem   = byteo & 16383;
    const int row   = rem >> 8;
    const int sb    = rem & 255;
    const int bc    = sb ^ ((row & 15) << 4);
    const float* src = W + (size_t)row * H_DIM + ch * KC + (bc >> 1);
    ushort8v o;
#pragma unroll
    for (int t = 0; t < 8; ++t) o[t] = f2bf(src[t]);
    *(ushort8v*)((char*)WS + byteo) = o;

    if (blockIdx.x == 0 && threadIdx.x == 0) {
        unsigned long long mb = 0;
        for (int t = 0; t < nids; ++t) {
            const int e = ids[t];
            if (e >= 0 && e < E_NUM) mb |= (1ull << e);
        }
        *(unsigned long long*)((char*)WS + MASK_OFF) = mb;
    }
}

// ---- main: grid 256 (1 block/CU), 1024 thr = 16 waves; wave w ->
// (kh=w&3, cg=(w>>2)&1, rg=w>>3): 32 rows x 32 experts over K-quarter kh;
// X AND W double-buffered in LDS -> ONE barrier per chunk. ----
__global__ __launch_bounds__(1024) void router_main(
    const float* __restrict__ X, const unsigned short* __restrict__ WS,
    float* __restrict__ out)
{
    const int tid  = threadIdx.x;
    const int lane = tid & 63;
    const int w    = tid >> 6;        // 0..15
    const int kh   = w & 3;           // K quarter of the chunk
    const int cg   = (w >> 2) & 1;    // experts half
    const int rg   = w >> 3;          // row half
    const int rb   = blockIdx.x * MROWS;
    const int fr32 = lane & 31;
    const int fo   = lane >> 5;

    __shared__ char LDSRAW[98304];
    // buffer p (p=0,1): XH at p*32768, XL at p*32768+16384 (16 KB each,
    // [64][256B xor16]); WT at 65536 + p*16384 (16 KB swizzled W-hi tile)

    // X staging: 8 f32/thread
    const int srow  = tid >> 4;               // 0..63
    const int sc8   = (tid & 15) * 8;         // f32 col base
    const float* xg = X + (size_t)(rb + srow) * H_DIM + sc8;
    const int xbyte = srow * 256 + ((sc8 * 2) ^ ((srow & 15) << 4));

    // W DMA: 16 B/thread/chunk, linear from pre-swizzled image
    const char* wimg = (const char*)WS;
    const int   woff = w * 1024 + lane * 16;

    // frag-read coords
    const int arow = rg * 32 + fr32;
    const int asw  = (arow & 15) << 4;
    const int brow = cg * 32 + fr32;
    const int bsw  = (brow & 15) << 4;

    f32x16 acc;
#pragma unroll
    for (int r = 0; r < 16; ++r) acc[r] = 0.f;

    // ---- prologue: chunk-0 staged into buffer 0; chunk-1 X in regs ----
    float4 px0 = *(const float4*)(xg);
    float4 px1 = *(const float4*)(xg + 4);
    gload_lds16(wimg + woff, LDSRAW + 65536 + woff);       // W ch0 -> WT0
    {
        float v[8] = {px0.x, px0.y, px0.z, px0.w, px1.x, px1.y, px1.z, px1.w};
        ushort8v hv, lv;
#pragma unroll
        for (int t = 0; t < 8; ++t) {
            const unsigned short hb = f2bf(v[t]);
            hv[t] = hb;
            lv[t] = f2bf(v[t] - bf2f(hb));
        }
        *(ushort8v*)(LDSRAW + xbyte)         = hv;          // XH0
        *(ushort8v*)(LDSRAW + 16384 + xbyte) = lv;          // XL0
    }
    px0 = *(const float4*)(xg + KC);
    px1 = *(const float4*)(xg + KC + 4);

    for (int ch = 0; ch < NCH; ++ch) {
        const int p = ch & 1;
        __syncthreads();   // drains chunk-ch X writes + W DMA + px regs
        // ---- stage chunk ch+1 into buffer p^1 (read by compute ch-1, done) ----
        if (ch + 1 < NCH) {
            float v[8] = {px0.x, px0.y, px0.z, px0.w, px1.x, px1.y, px1.z, px1.w};
            ushort8v hv, lv;
#pragma unroll
            for (int t = 0; t < 8; ++t) {
                const unsigned short hb = f2bf(v[t]);
                hv[t] = hb;
                lv[t] = f2bf(v[t] - bf2f(hb));
            }
            char* xb = LDSRAW + (p ^ 1) * 32768;
            *(ushort8v*)(xb + xbyte)         = hv;
            *(ushort8v*)(xb + 16384 + xbyte) = lv;
            gload_lds16(wimg + (size_t)(ch + 1) * WIMG + woff,
                        LDSRAW + 65536 + (p ^ 1) * 16384 + woff);
        }
        if (ch + 2 < NCH) {
            const float* xn = xg + (ch + 2) * KC;
            px0 = *(const float4*)(xn);
            px1 = *(const float4*)(xn + 4);
        }
        // ---- compute chunk ch from buffer p ----
        const char* xh = LDSRAW + p * 32768;
        const char* xl = xh + 16384;
        const char* wt = LDSRAW + 65536 + p * 16384;
#pragma unroll
        for (int ks = 0; ks < 2; ++ks) {
            const int kb = kh * 64 + ks * 32 + fo * 16;
            short8v ah = *(const short8v*)(xh + arow * 256 + (kb ^ asw));
            short8v al = *(const short8v*)(xl + arow * 256 + (kb ^ asw));
            short8v bh = *(const short8v*)(wt + brow * 256 + (kb ^ bsw));
            acc = __builtin_amdgcn_mfma_f32_32x32x16_bf16(ah, bh, acc, 0, 0, 0);
            acc = __builtin_amdgcn_mfma_f32_32x32x16_bf16(al, bh, acc, 0, 0, 0);
        }
    }

    // ---- scoreboard: 2-round deterministic merge into [2][64][68] f32 ----
    __syncthreads();                       // all compute done
    float* sm = (float*)LDSRAW;            // 34816 B <= 98304
    // C/D layout (m74/m101): col = lane&31, row = (r&3)+8*(r>>2)+4*(lane>>5)
    if (kh < 2) {
#pragma unroll
        for (int r = 0; r < 16; ++r) {
            const int row = (r & 3) + 8 * (r >> 2) + 4 * fo;
            sm[(kh * 64 + rg * 32 + row) * 68 + cg * 32 + fr32] = acc[r];
        }
    }
    __syncthreads();
    if (kh >= 2) {
#pragma unroll
        for (int r = 0; r < 16; ++r) {
            const int row = (r & 3) + 8 * (r >> 2) + 4 * fo;
            sm[((kh - 2) * 64 + rg * 32 + row) * 68 + cg * 32 + fr32] += acc[r];
        }
    }
    __syncthreads();
    if (w >= 4) return;                    // no barriers after this point

    const unsigned long long mbits =
        *(const unsigned long long*)((const char*)WS + MASK_OFF);

    const int fr = lane & 15;
    const int fq = lane >> 4;
    float* o_log = out;
    float* o_rw  = out + (size_t)T_ROWS * E_NUM;
    float* o_se  = o_rw + (size_t)T_ROWS * TOPK;

    // wave w handles rows w*16 .. w*16+15 with the value-verified epilogue
#pragma unroll
    for (int j = 0; j < 4; ++j) {
        const int row_l = w * 16 + fq * 4 + j;
        const int grow  = rb + row_l;
        float a0 = 0.f, a1 = 0.f, a2 = 0.f, a3 = 0.f;
#pragma unroll
        for (int p = 0; p < 2; ++p) {      // fixed-order plane reduction
            a0 += sm[(p * 64 + row_l) * 68 +  0 + fr];
            a1 += sm[(p * 64 + row_l) * 68 + 16 + fr];
            a2 += sm[(p * 64 + row_l) * 68 + 32 + fr];
            a3 += sm[(p * 64 + row_l) * 68 + 48 + fr];
        }
        float mv0 = ((mbits >> ( 0 + fr)) & 1) ? a0 : -10000.0f;
        float mv1 = ((mbits >> (16 + fr)) & 1) ? a1 : -10000.0f;
        float mv2 = ((mbits >> (32 + fr)) & 1) ? a2 : -10000.0f;
        float mv3 = ((mbits >> (48 + fr)) & 1) ? a3 : -10000.0f;
        o_log[(size_t)grow * 64 +  0 + fr] = mv0;
        o_log[(size_t)grow * 64 + 16 + fr] = mv1;
        o_log[(size_t)grow * 64 + 32 + fr] = mv2;
        o_log[(size_t)grow * 64 + 48 + fr] = mv3;

        float m = fmaxf(fmaxf(mv0, mv1), fmaxf(mv2, mv3));
#pragma unroll
        for (int off = 1; off < 16; off <<= 1) m = fmaxf(m, __shfl_xor(m, off));

        float tsum = 0.f, myv = 0.f;
        int   mye  = 0;
#pragma unroll
        for (int t = 0; t < TOPK; ++t) {
            float bv = mv0; int be = fr;
            if (mv1 > bv) { bv = mv1; be = 16 + fr; }
            if (mv2 > bv) { bv = mv2; be = 32 + fr; }
            if (mv3 > bv) { bv = mv3; be = 48 + fr; }
#pragma unroll
            for (int off = 1; off < 16; off <<= 1) {
                float ov = __shfl_xor(bv, off);
                int   oe = __shfl_xor(be, off);
                if (ov > bv || (ov == bv && oe < be)) { bv = ov; be = oe; }
            }
            const float pv = expf(bv - m);
            tsum += pv;
            if (fr == t) { myv = pv; mye = be; }
            if ((be & 15) == fr) {       // owner lane excludes winner
                const int bn = be >> 4;
                if      (bn == 0) mv0 = -3.4e38f;
                else if (bn == 1) mv1 = -3.4e38f;
                else if (bn == 2) mv2 = -3.4e38f;
                else              mv3 = -3.4e38f;
            }
        }
        if (fr < TOPK) {
            o_rw[(size_t)grow * TOPK + fr] = myv / tsum;
            o_se[(size_t)grow * TOPK + fr] = (float)mye;
        }
    }
}

extern "C" void kernel_launch(void* const* d_in, const int* in_sizes, int n_in,
                              void* d_out, int out_size, void* d_ws, size_t ws_size,
                              hipStream_t stream) {
    const float* X   = (const float*)d_in[0];
    const float* W   = (const float*)d_in[1];
    const int*   ids = (const int*)d_in[2];
    const int    nids = in_sizes[2];
    float* out = (float*)d_out;

    unsigned short* WS = (unsigned short*)d_ws;   // 512 KB W image + 8 B mask

    hipLaunchKernelGGL(prep_w, dim3(128), dim3(256), 0, stream, W, WS, ids, nids);
    hipLaunchKernelGGL(router_main, dim3(T_ROWS / MROWS), dim3(1024), 0, stream,
                       X, WS, out);
}